// Round 1
// baseline (218.456 us; speedup 1.0000x reference)
//
#include <hip/hip_runtime.h>
#include <math.h>

#define MEM 128
#define HSTR 136   // LDS row stride for h (bf16 elems): 272B, 16B-aligned, bank-balanced

typedef __bf16 bf16x8 __attribute__((ext_vector_type(8)));
typedef float  f32x4  __attribute__((ext_vector_type(4)));

__device__ __forceinline__ float fast_rcp(float x) { return __builtin_amdgcn_rcpf(x); }
__device__ __forceinline__ float fast_sigmoid(float x) {
    return fast_rcp(1.0f + __expf(-x));
}
__device__ __forceinline__ float fast_tanh(float x) {
    // 1 - 2/(e^{2x}+1): robust at +/-inf of exp
    return 1.0f - 2.0f * fast_rcp(__expf(2.0f * x) + 1.0f);
}

// ---------------- prep: normalization LUT + rank-1 input vectors ----------------
__global__ void prep_kernel(const float* __restrict__ numbers,
                            const float* __restrict__ w_num,
                            const float* __restrict__ b_num,
                            const float* __restrict__ W_ih,
                            const float* __restrict__ b_ih,
                            const float* __restrict__ b_hh,
                            float* __restrict__ mean_lut, float* __restrict__ inv_lut,
                            float* __restrict__ Avec, float* __restrict__ Bvec) {
    __shared__ float sx[100];
    int tid = threadIdx.x;
    if (tid < 100) sx[tid] = numbers[tid];
    __syncthreads();
    if (tid < 100) {
        float s = 0.f, ss = 0.f;
        for (int j = 0; j <= tid; ++j) { float v = sx[j]; s += v; ss += v * v; }
        float cap  = (float)(tid + 1);
        float mean = s / cap;
        float var  = ss / cap - mean * mean;
        if (var < 0.f) var = 0.f;
        float sd = sqrtf(var);
        float inv = (cap > 3.0f && sd > 1e-8f) ? (1.0f / sd) : 1.0f;
        mean_lut[tid] = mean;
        inv_lut[tid]  = inv;
    }
    // A[j] = sum_m W_ih[j][128+m]*w_num[m];  B[j] = sum_m W_ih[j][128+m]*b_num[m] + b_ih[j] + b_hh[j]
    if (tid < 512) {
        const float* row = W_ih + tid * 256 + 128;
        float a = 0.f, b = 0.f;
        #pragma unroll 8
        for (int m = 0; m < 128; ++m) { a += row[m] * w_num[m]; b += row[m] * b_num[m]; }
        Avec[tid] = a;
        Bvec[tid] = b + b_ih[tid] + b_hh[tid];
    }
}

// ---------------- main: 128-step LSTM over 16 batch rows per block ----------------
__global__ __launch_bounds__(512, 2) void lstm_kernel(
        const float* __restrict__ numbers, const float* __restrict__ W_hh,
        const float* __restrict__ W_fh,    const float* __restrict__ b_fh,
        const float* __restrict__ mean_lut, const float* __restrict__ inv_lut,
        const float* __restrict__ Avec,     const float* __restrict__ Bvec,
        float* __restrict__ fc_sum, float* __restrict__ hs_bar) {
    __shared__ unsigned short hbuf[2][16 * HSTR];   // h state, bf16, [row][col]
    __shared__ float xls[128 * 16];                 // normalized x, [t][row]

    const int tid  = threadIdx.x;
    const int lane = tid & 63;
    const int wave = tid >> 6;        // 0..7 -> gate-column group
    const int quad = lane >> 4;       // 0..3
    const int lcol = lane & 15;
    const int m0   = wave * 16;       // column offset within a gate (0..112)
    const int r0   = blockIdx.x * 16; // global batch row base

    // ---- load + normalize x into LDS [t][row] ----
    for (int i = tid; i < 16 * 128; i += 512) {
        int row = i >> 7;
        int t   = i & 127;
        int flat = (r0 + row) * 128 + t;
        int ii = (flat < 100) ? flat : 99;   // k>100 uses stats at k=100
        float v = numbers[flat];
        xls[t * 16 + row] = (v - mean_lut[ii]) * inv_lut[ii];
    }
    // ---- zero h buffer 0 (h0 = 0) ----
    for (int i = tid; i < 16 * HSTR; i += 512) hbuf[0][i] = 0;

    // ---- persistent W_hh B-fragments (bf16) in registers: [gate][kk] ----
    bf16x8 bf[4][4];
    #pragma unroll
    for (int g = 0; g < 4; ++g) {
        #pragma unroll
        for (int kk = 0; kk < 4; ++kk) {
            int j = g * 128 + m0 + lcol;            // gate output column (n)
            const float* p = W_hh + j * 128 + kk * 32 + quad * 8;
            f32x4 w0 = *(const f32x4*)p;
            f32x4 w1 = *(const f32x4*)(p + 4);
            bf16x8 bt;
            #pragma unroll
            for (int q = 0; q < 4; ++q) { bt[q] = (__bf16)w0[q]; bt[q + 4] = (__bf16)w1[q]; }
            bf[g][kk] = bt;
        }
    }
    // ---- rank-1 input coefficients for this lane's column ----
    float ag[4], bg[4];
    #pragma unroll
    for (int g = 0; g < 4; ++g) {
        ag[g] = Avec[g * 128 + m0 + lcol];
        bg[g] = Bvec[g * 128 + m0 + lcol];
    }

    float c[4]  = {0.f, 0.f, 0.f, 0.f};  // C-layout: row = quad*4+r, col = m0+lcol
    float hf[4] = {0.f, 0.f, 0.f, 0.f};
    __syncthreads();

    auto step = [&](int t, const unsigned short* hin, unsigned short* hout) {
        // A-fragments of h from LDS: A[m=lcol][k=kk*32+quad*8 ..+7]
        bf16x8 af[4];
        #pragma unroll
        for (int kk = 0; kk < 4; ++kk)
            af[kk] = *(const bf16x8*)(const void*)(hin + lcol * HSTR + kk * 32 + quad * 8);
        // x values for this lane's 4 rows (broadcast within quad)
        f32x4 xq = *(const f32x4*)(const void*)(xls + t * 16 + quad * 4);
        // gates = x*A + B + h @ W_hh^T
        f32x4 acc[4];
        #pragma unroll
        for (int g = 0; g < 4; ++g) {
            f32x4 a0;
            #pragma unroll
            for (int r = 0; r < 4; ++r) a0[r] = xq[r] * ag[g] + bg[g];
            #pragma unroll
            for (int kk = 0; kk < 4; ++kk)
                a0 = __builtin_amdgcn_mfma_f32_16x16x32_bf16(af[kk], bf[g][kk], a0, 0, 0, 0);
            acc[g] = a0;
        }
        // gate math + h write-back (bf16) to the other buffer
        #pragma unroll
        for (int r = 0; r < 4; ++r) {
            float si = fast_sigmoid(acc[0][r]);
            float sf = fast_sigmoid(acc[1][r]);
            float tg = fast_tanh(acc[2][r]);
            float so = fast_sigmoid(acc[3][r]);
            float c2 = sf * c[r] + si * tg;
            c[r] = c2;
            float h = so * fast_tanh(c2);
            hf[r] = h;
            hout[(quad * 4 + r) * HSTR + m0 + lcol] = __builtin_bit_cast(unsigned short, (__bf16)h);
        }
        __syncthreads();
    };

    for (int t = 0; t < 128; t += 2) {
        step(t,     hbuf[0], hbuf[1]);
        step(t + 1, hbuf[1], hbuf[0]);
    }
    // final h (t=127) lives in hbuf[0]; final c in regs; hf = final h (fp32)

    // ---- hs_bar partial: sum over this block's 16 rows ----
    float v = hf[0] + hf[1] + hf[2] + hf[3];
    v += __shfl_xor(v, 16);
    v += __shfl_xor(v, 32);
    if (lane < 16) atomicAdd(&hs_bar[m0 + lane], v);

    // ---- f_g = sigmoid(h @ W_fh^T + b_fh); fc partial = sum_rows f_g*c ----
    f32x4 facc;
    {
        float bb = b_fh[m0 + lcol];
        #pragma unroll
        for (int r = 0; r < 4; ++r) facc[r] = bb;
    }
    #pragma unroll
    for (int kk = 0; kk < 4; ++kk) {
        bf16x8 afr = *(const bf16x8*)(const void*)(hbuf[0] + lcol * HSTR + kk * 32 + quad * 8);
        const float* p = W_fh + (m0 + lcol) * 128 + kk * 32 + quad * 8;
        f32x4 w0 = *(const f32x4*)p;
        f32x4 w1 = *(const f32x4*)(p + 4);
        bf16x8 wt;
        #pragma unroll
        for (int q = 0; q < 4; ++q) { wt[q] = (__bf16)w0[q]; wt[q + 4] = (__bf16)w1[q]; }
        facc = __builtin_amdgcn_mfma_f32_16x16x32_bf16(afr, wt, facc, 0, 0, 0);
    }
    float fcv = 0.f;
    #pragma unroll
    for (int r = 0; r < 4; ++r) fcv += fast_sigmoid(facc[r]) * c[r];
    fcv += __shfl_xor(fcv, 16);
    fcv += __shfl_xor(fcv, 32);
    if (lane < 16) atomicAdd(&fc_sum[m0 + lane], fcv);
}

// ---------------- epilogue: root Tree-LSTM cell + output projection ----------------
__global__ void finalize_kernel(const float* __restrict__ fc_sum,
                                const float* __restrict__ hs_bar,
                                const float* __restrict__ W_iouh,
                                const float* __restrict__ b_iouh,
                                const float* __restrict__ W_lout,
                                const float* __restrict__ b_lout,
                                float* __restrict__ out) {
    __shared__ float hsb[128], iou[384], hfin[128];
    int tid = threadIdx.x;
    if (tid < 128) hsb[tid] = hs_bar[tid];
    __syncthreads();
    if (tid < 384) {
        float s = b_iouh[tid];
        const float* row = W_iouh + tid * 128;
        #pragma unroll 8
        for (int m = 0; m < 128; ++m) s += row[m] * hsb[m];
        iou[tid] = s;
    }
    __syncthreads();
    if (tid < 128) {
        float i = iou[tid], o = iou[128 + tid], u = iou[256 + tid];
        float cf = fast_sigmoid(i) * fast_tanh(u) + fc_sum[tid];
        out[tid] = cf;
        hfin[tid] = fast_sigmoid(o) * fast_tanh(cf);
    }
    __syncthreads();
    if (tid < 128) {
        float s = b_lout[tid];
        const float* row = W_lout + tid * 128;
        #pragma unroll 8
        for (int k = 0; k < 128; ++k) s += row[k] * hfin[k];
        out[128 + tid] = s;
    }
}

extern "C" void kernel_launch(void* const* d_in, const int* in_sizes, int n_in,
                              void* d_out, int out_size, void* d_ws, size_t ws_size,
                              hipStream_t stream) {
    const float* numbers = (const float*)d_in[0];
    const float* w_num   = (const float*)d_in[1];
    const float* b_num   = (const float*)d_in[2];
    const float* W_ih    = (const float*)d_in[3];
    const float* W_hh    = (const float*)d_in[4];
    const float* b_ih    = (const float*)d_in[5];
    const float* b_hh    = (const float*)d_in[6];
    const float* W_fh    = (const float*)d_in[7];
    const float* b_fh    = (const float*)d_in[8];
    const float* W_iouh  = (const float*)d_in[9];
    const float* b_iouh  = (const float*)d_in[10];
    const float* W_lout  = (const float*)d_in[11];
    const float* b_lout  = (const float*)d_in[12];
    float* out = (float*)d_out;

    float* ws       = (float*)d_ws;
    float* fc_sum   = ws;         // 128
    float* hs_bar   = ws + 128;   // 128
    float* mean_lut = ws + 256;   // 100
    float* inv_lut  = ws + 356;   // 100
    float* Avec     = ws + 456;   // 512
    float* Bvec     = ws + 968;   // 512

    hipMemsetAsync(fc_sum, 0, 256 * sizeof(float), stream);  // zero fc_sum + hs_bar
    prep_kernel<<<1, 512, 0, stream>>>(numbers, w_num, b_num, W_ih, b_ih, b_hh,
                                       mean_lut, inv_lut, Avec, Bvec);
    lstm_kernel<<<256, 512, 0, stream>>>(numbers, W_hh, W_fh, b_fh,
                                         mean_lut, inv_lut, Avec, Bvec, fc_sum, hs_bar);
    finalize_kernel<<<1, 384, 0, stream>>>(fc_sum, hs_bar, W_iouh, b_iouh, W_lout, b_lout, out);
}